// Round 13
// baseline (137.831 us; speedup 1.0000x reference)
//
#include <hip/hip_runtime.h>
#include <stddef.h>

#define CCH 128   // channels
#define CAP 64    // bucket slots per vertex (Poisson(16) -> P(deg>=64) ~ 1e-19)
#define NBIN 8    // one bin per XCD
#define BIN_CS 4096   // edges per bin_edges block

typedef unsigned int  uint;
typedef unsigned short ushort;
typedef short bf16x8 __attribute__((ext_vector_type(8)));
typedef float f32x4  __attribute__((ext_vector_type(4)));

__device__ __forceinline__ ushort f2bf(float f) {        // RNE float->bf16
    uint b = __float_as_uint(f);
    b += 0x7FFFu + ((b >> 16) & 1u);
    return (ushort)(b >> 16);
}
__device__ __forceinline__ float bflo(uint u) { return __uint_as_float(u << 16); }
__device__ __forceinline__ float bfhi(uint u) { return __uint_as_float(u & 0xFFFF0000u); }

// ---------------- prep: W_stack bf16 [o][0:128]=W1-W2, [o][128:256]=W2
//                  + zero counts + bin_cnt (adjacent)
__global__ void prep_zero(const float* __restrict__ w, ushort* __restrict__ wstb,
                          int* __restrict__ zero_buf, int NZ) {
    int i = blockIdx.x * 256 + threadIdx.x;    // 128 blocks -> 32768
    if (i < CCH * 256) {
        int c = i & 255;
        float v = w[i];
        if (c < 128) v -= w[i + 128];          // w1 - w2 (same row, +128 cols)
        wstb[i] = f2bf(v);
    }
    for (int n = i; n < NZ; n += gridDim.x * 256) zero_buf[n] = 0;
}

// ---------------- pure transpose x [128][N] -> x_t bf16 [N][128]
__global__ __launch_bounds__(256) void transpose_bf16(
        const float* __restrict__ x, ushort* __restrict__ xtb, int N) {
    __shared__ float tile[CCH][33];
    int n0 = blockIdx.x * 32;
    int tid = threadIdx.x;
    {
        int tx = tid & 31, r = tid >> 5;
        int n = n0 + tx;
        #pragma unroll
        for (int k = 0; k < 16; ++k) {
            int c = k * 8 + r;
            tile[c][tx] = (n < N) ? x[(size_t)c * N + n] : 0.f;
        }
    }
    __syncthreads();
    #pragma unroll
    for (int p = 0; p < 2; ++p) {
        int nn = p * 16 + (tid >> 4);          // vertex within tile
        int c8 = (tid & 15) * 8;               // 8 consecutive channels
        if (n0 + nn < N) {
            ushort u[8];
            #pragma unroll
            for (int j = 0; j < 8; ++j) u[j] = f2bf(tile[c8 + j][nn]);
            uint4 v;
            v.x = (uint)u[0] | ((uint)u[1] << 16);
            v.y = (uint)u[2] | ((uint)u[3] << 16);
            v.z = (uint)u[4] | ((uint)u[5] << 16);
            v.w = (uint)u[6] | ((uint)u[7] << 16);
            *(uint4*)(xtb + (size_t)(n0 + nn) * CCH + c8) = v;   // full 256B rows
        }
    }
}

// ---------------- phase 1: bin edges by r-partition (packed (r,g) appends)
__global__ __launch_bounds__(256) void bin_edges(
        const int* __restrict__ ridx, const int* __restrict__ gidx,
        int* __restrict__ bin_cnt, int2* __restrict__ binrg,
        int E, int psz, int bcap) {
    __shared__ int lcnt[NBIN], lbase[NBIN], lcur[NBIN];
    int e0 = blockIdx.x * BIN_CS;
    int tid = threadIdx.x;
    if (tid < NBIN) lcnt[tid] = 0;
    __syncthreads();
    int rr[16], gg[16], pp[16];
    #pragma unroll
    for (int q = 0; q < 16; ++q) {
        int e = e0 + q * 256 + tid;
        bool in = (e < E);
        rr[q] = in ? ridx[e] : 0;
        gg[q] = in ? gidx[e] : 0;
        pp[q] = in ? (rr[q] / psz) : -1;
        if (pp[q] >= 0) atomicAdd(&lcnt[pp[q]], 1);    // LDS atomic
    }
    __syncthreads();
    if (tid < NBIN) { lbase[tid] = atomicAdd(&bin_cnt[tid], lcnt[tid]); lcur[tid] = 0; }
    __syncthreads();
    #pragma unroll
    for (int q = 0; q < 16; ++q) {
        if (pp[q] >= 0) {
            int s = atomicAdd(&lcur[pp[q]], 1);        // LDS atomic
            int idx = lbase[pp[q]] + s;
            if (idx < bcap)
                binrg[(size_t)pp[q] * bcap + idx] = make_int2(rr[q], gg[q]);
        }
    }
}

// ---------------- phase 2: per-XCD bucket fill; bin p's counts+bucket working
// set (~1.6MB) stays resident in XCD p's L2 -> one writeback per line.
__global__ __launch_bounds__(256) void fill_from_bins(
        const int2* __restrict__ binrg, const int* __restrict__ bin_cnt,
        int* __restrict__ counts, int* __restrict__ bucket, int bcap, int kb) {
    int p   = blockIdx.x & 7;          // round-robin -> XCD id
    int blk = blockIdx.x >> 3;         // block within partition group
    int cnt = bin_cnt[p];
    if (cnt > bcap) cnt = bcap;
    const int2* bp = binrg + (size_t)p * bcap;
    for (int base = blk * 1024; base < cnt; base += kb * 1024) {
        int2 u[4]; bool act[4];
        #pragma unroll
        for (int q = 0; q < 4; ++q) {
            int i = base + q * 256 + threadIdx.x;
            act[q] = (i < cnt);
            u[q] = act[q] ? bp[i] : make_int2(0, 0);
        }
        #pragma unroll
        for (int q = 0; q < 4; ++q) {
            if (act[q]) {
                int pos = atomicAdd(&counts[u[q].x], 1);
                if (pos < CAP) bucket[u[q].x * CAP + pos] = u[q].y;
            }
        }
    }
}

// ---------------- gather-mean over bf16 x_t: one wave per vertex, bf16 output
__global__ __launch_bounds__(256) void gather_mean(
        const uint2* __restrict__ xtb,      // [N][32] uint2 = bf16x4 quads
        const int*   __restrict__ counts,   // [N] degrees
        const int*   __restrict__ bucket,   // [N][CAP]
        ushort*      __restrict__ gmb,      // [N][128] bf16
        int N) {
    int wave = threadIdx.x >> 6;
    int l = threadIdx.x & 63;
    int lq = l & 31;          // channel quad
    int half = l >> 5;        // edge-pair half
    #pragma unroll
    for (int i = 0; i < 2; ++i) {
        int n = blockIdx.x * 8 + wave * 2 + i;
        if (n >= N) return;   // wave-uniform
        int deg = __builtin_amdgcn_readfirstlane(counts[n]);
        int dg  = (deg < CAP) ? deg : CAP;
        const int* row = bucket + n * CAP;
        float4 acc = make_float4(0.f, 0.f, 0.f, 0.f);
        int k = 0;
        for (; k + 16 <= dg; k += 16) {         // 8 outstanding 8B gathers/lane
            uint2 u[8];
            #pragma unroll
            for (int q = 0; q < 8; ++q) {
                int g = row[k + 2 * q + half];
                u[q] = xtb[(size_t)g * 32 + lq];
            }
            #pragma unroll
            for (int q = 0; q < 8; ++q) {
                acc.x += bflo(u[q].x); acc.y += bfhi(u[q].x);
                acc.z += bflo(u[q].y); acc.w += bfhi(u[q].y);
            }
        }
        for (; k + 8 <= dg; k += 8) {
            uint2 u[4];
            #pragma unroll
            for (int q = 0; q < 4; ++q) {
                int g = row[k + 2 * q + half];
                u[q] = xtb[(size_t)g * 32 + lq];
            }
            #pragma unroll
            for (int q = 0; q < 4; ++q) {
                acc.x += bflo(u[q].x); acc.y += bfhi(u[q].x);
                acc.z += bflo(u[q].y); acc.w += bfhi(u[q].y);
            }
        }
        for (; k + 2 <= dg; k += 2) {
            int g = row[k + half];
            uint2 u = xtb[(size_t)g * 32 + lq];
            acc.x += bflo(u.x); acc.y += bfhi(u.x);
            acc.z += bflo(u.y); acc.w += bfhi(u.y);
        }
        if (k < dg && half == 0) {
            int g = row[k];
            uint2 u = xtb[(size_t)g * 32 + lq];
            acc.x += bflo(u.x); acc.y += bfhi(u.x);
            acc.z += bflo(u.y); acc.w += bfhi(u.y);
        }
        acc.x += __shfl_xor(acc.x, 32);
        acc.y += __shfl_xor(acc.y, 32);
        acc.z += __shfl_xor(acc.z, 32);
        acc.w += __shfl_xor(acc.w, 32);
        float inv = (deg > 0) ? 1.f / (float)deg : 0.f;
        if (half == 0) {
            ushort4 r;
            r.x = f2bf(acc.x * inv);
            r.y = f2bf(acc.y * inv);
            r.z = f2bf(acc.z * inv);
            r.w = f2bf(acc.w * inv);
            *(ushort4*)(gmb + (size_t)n * CCH + lq * 4) = r;
        }
    }
}

// ---------------- MFMA gemm: out = mask * leaky(W_stack @ [x;gmean] + bias)
__global__ __launch_bounds__(256) void gemm_mfma(
        const ushort* __restrict__ wstb,    // [128][256] bf16
        const ushort* __restrict__ xtb,     // [N][128] bf16  (K 0..127)
        const ushort* __restrict__ gmb,     // [N][128] bf16  (K 128..255)
        const int*    __restrict__ counts,  // [N]
        const float*  __restrict__ bias,    // [128]
        float* __restrict__ out,            // [128][N]
        int N) {
    int t = threadIdx.x;
    int wv = t >> 6;       // wave 0..3 -> n-frag
    int l  = t & 63;
    int l15 = l & 15;      // A: M-row / B: N-col / D: N-col
    int lk  = l >> 4;      // k-group (0..3)
    int n = blockIdx.x * 64 + wv * 16 + l15;
    int nc = (n < N) ? n : (N - 1);          // clamped for loads

    f32x4 acc[8];
    #pragma unroll
    for (int mf = 0; mf < 8; ++mf) acc[mf] = (f32x4){0.f, 0.f, 0.f, 0.f};

    const ushort* brow_x = xtb + (size_t)nc * CCH + lk * 8;
    const ushort* brow_g = gmb + (size_t)nc * CCH + lk * 8;
    const ushort* arow   = wstb + (size_t)l15 * 256 + lk * 8;

    #pragma unroll
    for (int ks = 0; ks < 8; ++ks) {
        const ushort* bp = (ks < 4) ? (brow_x + ks * 32) : (brow_g + (ks - 4) * 32);
        bf16x8 b = *(const bf16x8*)bp;
        #pragma unroll
        for (int mf = 0; mf < 8; ++mf) {
            bf16x8 a = *(const bf16x8*)(arow + (size_t)mf * 16 * 256 + ks * 32);
            acc[mf] = __builtin_amdgcn_mfma_f32_16x16x32_bf16(a, b, acc[mf], 0, 0, 0);
        }
    }

    // epilogue: D row(o) = mf*16 + lk*4 + r, col(n) = lane&15
    if (n < N) {
        float m = (counts[n] > 0) ? 1.f : 0.f;
        #pragma unroll
        for (int mf = 0; mf < 8; ++mf) {
            #pragma unroll
            for (int r = 0; r < 4; ++r) {
                int o = mf * 16 + lk * 4 + r;
                float v = (acc[mf][r] + bias[o]) * m;
                v = (v >= 0.f) ? v : 0.3f * v;
                out[(size_t)o * N + n] = v;
            }
        }
    }
}

extern "C" void kernel_launch(void* const* d_in, const int* in_sizes, int n_in,
                              void* d_out, int out_size, void* d_ws, size_t ws_size,
                              hipStream_t stream) {
    const float* x      = (const float*)d_in[0];  // [1,128,N]
    const float* weight = (const float*)d_in[1];  // [128,256]
    const float* bias   = (const float*)d_in[2];  // [128]
    const int*   ridx   = (const int*)d_in[3];    // [E]
    const int*   gidx   = (const int*)d_in[4];    // [E]
    float* out = (float*)d_out;

    int N = in_sizes[0] / CCH;   // 50000
    int E = in_sizes[3];         // 800000

    int psz  = (N + 7) / 8;                    // vertices per partition
    int bcap = E / NBIN + (E / 32) + 1024;     // per-bin capacity (+~80 sigma)

    char* ws = (char*)d_ws;
    size_t xtb_bytes = (((size_t)N * CCH * sizeof(ushort)) + 63) & ~(size_t)63;
    size_t n_bytes   = (((size_t)N * sizeof(int)) + 63) & ~(size_t)63;
    size_t bkt_bytes = (((size_t)N * CAP * sizeof(int)) + 63) & ~(size_t)63;
    size_t w_bytes   = (((size_t)CCH * 256 * sizeof(ushort)) + 63) & ~(size_t)63;
    size_t bin_bytes = (((size_t)NBIN * bcap * sizeof(int2)) + 63) & ~(size_t)63;

    size_t o = 0;
    ushort* xtb    = (ushort*)(ws + o); o += xtb_bytes;
    int*    counts = (int*)   (ws + o); o += n_bytes;   // n_bytes is 64-aligned
    int*    bin_cnt= (int*)   (ws + o); o += 64;
    int*    bucket = (int*)   (ws + o); o += bkt_bytes;
    ushort* wstb   = (ushort*)(ws + o); o += w_bytes;
    ushort* gmb    = (ushort*)(ws + o); o += xtb_bytes;
    int2*   binrg  = (int2*)  (ws + o); o += bin_bytes;

    // 1. weights prep (bf16 W_stack) + zero counts & bin_cnt
    prep_zero<<<128, 256, 0, stream>>>(weight, wstb, counts, N + 16);

    // 2. transpose to bf16 (full-row writes)
    transpose_bf16<<<(N + 31) / 32, 256, 0, stream>>>(x, xtb, N);

    // 3. phase 1: bin edges by r-partition (one pass, packed appends)
    int bblocks = (E + BIN_CS - 1) / BIN_CS;
    bin_edges<<<bblocks, 256, 0, stream>>>(ridx, gidx, bin_cnt, binrg, E, psz, bcap);

    // 4. phase 2: per-XCD bucket fill (L2-resident working set)
    int kb = 128;                               // blocks per partition group
    fill_from_bins<<<kb * NBIN, 256, 0, stream>>>(binrg, bin_cnt, counts, bucket,
                                                  bcap, kb);

    // 5. gather-mean (bf16 reads, fp32 accumulate, bf16 output)
    gather_mean<<<(N + 7) / 8, 256, 0, stream>>>(
        (const uint2*)xtb, counts, bucket, gmb, N);

    // 6. single bf16 MFMA GEMM + bias + mask + leaky
    gemm_mfma<<<(N + 63) / 64, 256, 0, stream>>>(
        wstb, xtb, gmb, counts, bias, out, N);
}

// Round 14
// 136.281 us; speedup vs baseline: 1.0114x; 1.0114x over previous
//
#include <hip/hip_runtime.h>
#include <stddef.h>

#define CCH 128   // channels
#define CAP 64    // bucket slots per vertex (Poisson(16) -> P(deg>=64) ~ 1e-19)
#define FILL_CS 4096   // edges per chunk for XCD-partitioned fill

typedef unsigned int  uint;
typedef unsigned short ushort;
typedef short bf16x8 __attribute__((ext_vector_type(8)));
typedef float f32x4  __attribute__((ext_vector_type(4)));

__device__ __forceinline__ ushort f2bf(float f) {        // RNE float->bf16
    uint b = __float_as_uint(f);
    b += 0x7FFFu + ((b >> 16) & 1u);
    return (ushort)(b >> 16);
}
__device__ __forceinline__ float bflo(uint u) { return __uint_as_float(u << 16); }
__device__ __forceinline__ float bfhi(uint u) { return __uint_as_float(u & 0xFFFF0000u); }

// ---------------- prep: W_stack bf16 [o][0:128]=W1-W2, [o][128:256]=W2
//                  + zero counts (cursor/degree array)
__global__ void prep_zero(const float* __restrict__ w, ushort* __restrict__ wstb,
                          int* __restrict__ zero_buf, int NZ) {
    int i = blockIdx.x * 256 + threadIdx.x;    // 128 blocks -> 32768
    if (i < CCH * 256) {
        int c = i & 255;
        float v = w[i];
        if (c < 128) v -= w[i + 128];          // w1 - w2 (same row, +128 cols)
        wstb[i] = f2bf(v);
    }
    for (int n = i; n < NZ; n += gridDim.x * 256) zero_buf[n] = 0;
}

// ---------------- fused heterogeneous dispatch:
//   transpose blocks: x [128][N] -> xtb bf16 [N][128]        (BW-bound)
//   fill blocks:      one-pass bucket CSR, XCD-partitioned   (latency-bound)
// All stream-once reads are NON-TEMPORAL (nt) so they don't evict the
// dirty bucket/counts lines from the owning XCD's L2.
__global__ __launch_bounds__(256) void transpose_fill(
        const float* __restrict__ x, ushort* __restrict__ xtb,
        const int* __restrict__ ridx, const int* __restrict__ gidx,
        int* __restrict__ counts, int* __restrict__ bucket,
        int N, int E, int psz, int T, int F) {
    __shared__ float tile[CCH][33];
    int b = blockIdx.x;
    int mtf = (T < F) ? T : F;
    int twice = 2 * mtf;
    bool is_t; int sub;
    if (b < twice) { is_t = !(b & 1); sub = b >> 1; }
    else           { is_t = (T > F);  sub = (b - twice) + mtf; }
    int tid = threadIdx.x;

    if (is_t) {
        // ---- transpose tile 'sub' (32 vertices, all 128 channels)
        int n0 = sub * 32;
        {
            int tx = tid & 31, r = tid >> 5;
            int n = n0 + tx;
            #pragma unroll
            for (int k = 0; k < 16; ++k) {
                int c = k * 8 + r;
                tile[c][tx] = (n < N) ?
                    __builtin_nontemporal_load(x + (size_t)c * N + n) : 0.f;
            }
        }
        __syncthreads();
        #pragma unroll
        for (int p = 0; p < 2; ++p) {
            int nn = p * 16 + (tid >> 4);          // vertex within tile
            int c8 = (tid & 15) * 8;               // 8 consecutive channels
            if (n0 + nn < N) {
                ushort u[8];
                #pragma unroll
                for (int j = 0; j < 8; ++j) u[j] = f2bf(tile[c8 + j][nn]);
                uint4 v;
                v.x = (uint)u[0] | ((uint)u[1] << 16);
                v.y = (uint)u[2] | ((uint)u[3] << 16);
                v.z = (uint)u[4] | ((uint)u[5] << 16);
                v.w = (uint)u[6] | ((uint)u[7] << 16);
                *(uint4*)(xtb + (size_t)(n0 + nn) * CCH + c8) = v;   // full 256B rows
            }
        }
    } else {
        // ---- bucket fill chunk: counts[r] is cursor AND degree; row base r*CAP.
        // 4-way ILP; nt loads keep bucket lines resident in this XCD's L2.
        int part  = sub & 7;           // round-robin -> XCD id
        int chunk = sub >> 3;
        int e0 = chunk * FILL_CS;
        int e1 = e0 + FILL_CS; if (e1 > E) e1 = E;
        for (int base = e0; base < e1; base += 1024) {
            int rr[4], gg[4];
            bool act[4];
            #pragma unroll
            for (int q = 0; q < 4; ++q) {
                int e = base + q * 256 + tid;
                bool in = (e < e1);
                int ec = in ? e : e0;
                rr[q] = __builtin_nontemporal_load(ridx + ec);
                gg[q] = __builtin_nontemporal_load(gidx + ec);
                act[q] = in && (rr[q] / psz == part);
            }
            #pragma unroll
            for (int q = 0; q < 4; ++q) {
                if (act[q]) {
                    int p = atomicAdd(&counts[rr[q]], 1);
                    if (p < CAP) bucket[rr[q] * CAP + p] = gg[q];
                }
            }
        }
    }
}

// ---------------- gather-mean over bf16 x_t: one wave per vertex, bf16 output
__global__ __launch_bounds__(256) void gather_mean(
        const uint2* __restrict__ xtb,      // [N][32] uint2 = bf16x4 quads
        const int*   __restrict__ counts,   // [N] degrees
        const int*   __restrict__ bucket,   // [N][CAP]
        ushort*      __restrict__ gmb,      // [N][128] bf16
        int N) {
    int wave = threadIdx.x >> 6;
    int l = threadIdx.x & 63;
    int lq = l & 31;          // channel quad
    int half = l >> 5;        // edge-pair half
    #pragma unroll
    for (int i = 0; i < 2; ++i) {
        int n = blockIdx.x * 8 + wave * 2 + i;
        if (n >= N) return;   // wave-uniform
        int deg = __builtin_amdgcn_readfirstlane(counts[n]);
        int dg  = (deg < CAP) ? deg : CAP;
        const int* row = bucket + n * CAP;
        float4 acc = make_float4(0.f, 0.f, 0.f, 0.f);
        int k = 0;
        for (; k + 16 <= dg; k += 16) {         // 8 outstanding 8B gathers/lane
            uint2 u[8];
            #pragma unroll
            for (int q = 0; q < 8; ++q) {
                int g = __builtin_nontemporal_load(row + k + 2 * q + half);
                u[q] = xtb[(size_t)g * 32 + lq];
            }
            #pragma unroll
            for (int q = 0; q < 8; ++q) {
                acc.x += bflo(u[q].x); acc.y += bfhi(u[q].x);
                acc.z += bflo(u[q].y); acc.w += bfhi(u[q].y);
            }
        }
        for (; k + 8 <= dg; k += 8) {
            uint2 u[4];
            #pragma unroll
            for (int q = 0; q < 4; ++q) {
                int g = __builtin_nontemporal_load(row + k + 2 * q + half);
                u[q] = xtb[(size_t)g * 32 + lq];
            }
            #pragma unroll
            for (int q = 0; q < 4; ++q) {
                acc.x += bflo(u[q].x); acc.y += bfhi(u[q].x);
                acc.z += bflo(u[q].y); acc.w += bfhi(u[q].y);
            }
        }
        for (; k + 2 <= dg; k += 2) {
            int g = __builtin_nontemporal_load(row + k + half);
            uint2 u = xtb[(size_t)g * 32 + lq];
            acc.x += bflo(u.x); acc.y += bfhi(u.x);
            acc.z += bflo(u.y); acc.w += bfhi(u.y);
        }
        if (k < dg && half == 0) {
            int g = __builtin_nontemporal_load(row + k);
            uint2 u = xtb[(size_t)g * 32 + lq];
            acc.x += bflo(u.x); acc.y += bfhi(u.x);
            acc.z += bflo(u.y); acc.w += bfhi(u.y);
        }
        acc.x += __shfl_xor(acc.x, 32);
        acc.y += __shfl_xor(acc.y, 32);
        acc.z += __shfl_xor(acc.z, 32);
        acc.w += __shfl_xor(acc.w, 32);
        float inv = (deg > 0) ? 1.f / (float)deg : 0.f;
        if (half == 0) {
            ushort4 r;
            r.x = f2bf(acc.x * inv);
            r.y = f2bf(acc.y * inv);
            r.z = f2bf(acc.z * inv);
            r.w = f2bf(acc.w * inv);
            *(ushort4*)(gmb + (size_t)n * CCH + lq * 4) = r;
        }
    }
}

// ---------------- MFMA gemm: out = mask * leaky(W_stack @ [x;gmean] + bias)
// N_TILE=64, 4 waves, each wave: 16 n-cols x 128 o-rows, K=256. No LDS, no barrier.
__global__ __launch_bounds__(256) void gemm_mfma(
        const ushort* __restrict__ wstb,    // [128][256] bf16
        const ushort* __restrict__ xtb,     // [N][128] bf16  (K 0..127)
        const ushort* __restrict__ gmb,     // [N][128] bf16  (K 128..255)
        const int*    __restrict__ counts,  // [N]
        const float*  __restrict__ bias,    // [128]
        float* __restrict__ out,            // [128][N]
        int N) {
    int t = threadIdx.x;
    int wv = t >> 6;       // wave 0..3 -> n-frag
    int l  = t & 63;
    int l15 = l & 15;      // A: M-row / B: N-col / D: N-col
    int lk  = l >> 4;      // k-group (0..3)
    int n = blockIdx.x * 64 + wv * 16 + l15;
    int nc = (n < N) ? n : (N - 1);          // clamped for loads

    f32x4 acc[8];
    #pragma unroll
    for (int mf = 0; mf < 8; ++mf) acc[mf] = (f32x4){0.f, 0.f, 0.f, 0.f};

    const ushort* brow_x = xtb + (size_t)nc * CCH + lk * 8;
    const ushort* brow_g = gmb + (size_t)nc * CCH + lk * 8;
    const ushort* arow   = wstb + (size_t)l15 * 256 + lk * 8;

    #pragma unroll
    for (int ks = 0; ks < 8; ++ks) {
        const ushort* bp = (ks < 4) ? (brow_x + ks * 32) : (brow_g + (ks - 4) * 32);
        bf16x8 b = *(const bf16x8*)bp;
        #pragma unroll
        for (int mf = 0; mf < 8; ++mf) {
            bf16x8 a = *(const bf16x8*)(arow + (size_t)mf * 16 * 256 + ks * 32);
            acc[mf] = __builtin_amdgcn_mfma_f32_16x16x32_bf16(a, b, acc[mf], 0, 0, 0);
        }
    }

    // epilogue: D row(o) = mf*16 + lk*4 + r, col(n) = lane&15
    if (n < N) {
        float m = (counts[n] > 0) ? 1.f : 0.f;
        #pragma unroll
        for (int mf = 0; mf < 8; ++mf) {
            #pragma unroll
            for (int r = 0; r < 4; ++r) {
                int o = mf * 16 + lk * 4 + r;
                float v = (acc[mf][r] + bias[o]) * m;
                v = (v >= 0.f) ? v : 0.3f * v;
                out[(size_t)o * N + n] = v;
            }
        }
    }
}

extern "C" void kernel_launch(void* const* d_in, const int* in_sizes, int n_in,
                              void* d_out, int out_size, void* d_ws, size_t ws_size,
                              hipStream_t stream) {
    const float* x      = (const float*)d_in[0];  // [1,128,N]
    const float* weight = (const float*)d_in[1];  // [128,256]
    const float* bias   = (const float*)d_in[2];  // [128]
    const int*   ridx   = (const int*)d_in[3];    // [E]
    const int*   gidx   = (const int*)d_in[4];    // [E]
    float* out = (float*)d_out;

    int N = in_sizes[0] / CCH;   // 50000
    int E = in_sizes[3];         // 800000

    char* ws = (char*)d_ws;
    size_t xtb_bytes = (((size_t)N * CCH * sizeof(ushort)) + 63) & ~(size_t)63;
    size_t n_bytes   = (((size_t)N * sizeof(int)) + 63) & ~(size_t)63;
    size_t bkt_bytes = (((size_t)N * CAP * sizeof(int)) + 63) & ~(size_t)63;
    size_t w_bytes   = (((size_t)CCH * 256 * sizeof(ushort)) + 63) & ~(size_t)63;

    size_t o = 0;
    ushort* xtb   = (ushort*)(ws + o); o += xtb_bytes;
    int*    counts= (int*)   (ws + o); o += n_bytes;
    int*    bucket= (int*)   (ws + o); o += bkt_bytes;
    ushort* wstb  = (ushort*)(ws + o); o += w_bytes;
    ushort* gmb   = (ushort*)(ws + o);

    int psz     = (N + 7) / 8;
    int nchunks = (E + FILL_CS - 1) / FILL_CS;
    int T = (N + 31) / 32;        // transpose blocks
    int F = nchunks * 8;          // fill blocks

    // 1. weights prep (bf16 W_stack) + zero counts
    prep_zero<<<128, 256, 0, stream>>>(weight, wstb, counts, N);

    // 2. fused transpose + bucket-CSR build (heterogeneous, interleaved blocks)
    transpose_fill<<<T + F, 256, 0, stream>>>(x, xtb, ridx, gidx,
                                              counts, bucket, N, E, psz, T, F);

    // 3. gather-mean (bf16 reads, fp32 accumulate, bf16 output)
    gather_mean<<<(N + 7) / 8, 256, 0, stream>>>(
        (const uint2*)xtb, counts, bucket, gmb, N);

    // 4. single bf16 MFMA GEMM + bias + mask + leaky
    gemm_mfma<<<(N + 63) / 64, 256, 0, stream>>>(
        wstb, xtb, gmb, counts, bias, out, N);
}

// Round 15
// 120.954 us; speedup vs baseline: 1.1395x; 1.1267x over previous
//
#include <hip/hip_runtime.h>
#include <stddef.h>

#define CCH 128   // channels
#define CAP 64    // bucket slots per vertex (Poisson(16) -> P(deg>=64) ~ 1e-19)
#define FILL_CS 4096   // edges per chunk for XCD-partitioned fill

typedef unsigned int  uint;
typedef unsigned short ushort;
typedef short bf16x8 __attribute__((ext_vector_type(8)));
typedef float f32x4  __attribute__((ext_vector_type(4)));

__device__ __forceinline__ ushort f2bf(float f) {        // RNE float->bf16
    uint b = __float_as_uint(f);
    b += 0x7FFFu + ((b >> 16) & 1u);
    return (ushort)(b >> 16);
}
__device__ __forceinline__ float bflo(uint u) { return __uint_as_float(u << 16); }
__device__ __forceinline__ float bfhi(uint u) { return __uint_as_float(u & 0xFFFF0000u); }

// ---------------- prep: W_stack bf16 [o][0:128]=W1-W2, [o][128:256]=W2
//                  + zero counts (cursor/degree array)
__global__ void prep_zero(const float* __restrict__ w, ushort* __restrict__ wstb,
                          int* __restrict__ zero_buf, int NZ) {
    int i = blockIdx.x * 256 + threadIdx.x;    // 128 blocks -> 32768
    if (i < CCH * 256) {
        int c = i & 255;
        float v = w[i];
        if (c < 128) v -= w[i + 128];          // w1 - w2 (same row, +128 cols)
        wstb[i] = f2bf(v);
    }
    for (int n = i; n < NZ; n += gridDim.x * 256) zero_buf[n] = 0;
}

// ---------------- fused heterogeneous dispatch:
//   transpose blocks: x [128][N] -> xtb bf16 [N][128]        (BW-bound)
//   fill blocks:      one-pass bucket CSR, XCD-partitioned   (latency-bound)
// KEY: all writers of counts[r]/bucket[r] are on ONE XCD (partitioned), so the
// cursor RMW does NOT need device scope. Workgroup-scope atomic executes at the
// owning XCD's L2 and the line stays cached -> short RTT, one writeback/line.
__global__ __launch_bounds__(256) void transpose_fill(
        const float* __restrict__ x, ushort* __restrict__ xtb,
        const int* __restrict__ ridx, const int* __restrict__ gidx,
        int* __restrict__ counts, int* __restrict__ bucket,
        int N, int E, int psz, int T, int F) {
    __shared__ float tile[CCH][33];
    int b = blockIdx.x;
    int mtf = (T < F) ? T : F;
    int twice = 2 * mtf;
    bool is_t; int sub;
    if (b < twice) { is_t = !(b & 1); sub = b >> 1; }
    else           { is_t = (T > F);  sub = (b - twice) + mtf; }
    int tid = threadIdx.x;

    if (is_t) {
        // ---- transpose tile 'sub' (32 vertices, all 128 channels)
        int n0 = sub * 32;
        {
            int tx = tid & 31, r = tid >> 5;
            int n = n0 + tx;
            #pragma unroll
            for (int k = 0; k < 16; ++k) {
                int c = k * 8 + r;
                tile[c][tx] = (n < N) ? x[(size_t)c * N + n] : 0.f;
            }
        }
        __syncthreads();
        #pragma unroll
        for (int p = 0; p < 2; ++p) {
            int nn = p * 16 + (tid >> 4);          // vertex within tile
            int c8 = (tid & 15) * 8;               // 8 consecutive channels
            if (n0 + nn < N) {
                ushort u[8];
                #pragma unroll
                for (int j = 0; j < 8; ++j) u[j] = f2bf(tile[c8 + j][nn]);
                uint4 v;
                v.x = (uint)u[0] | ((uint)u[1] << 16);
                v.y = (uint)u[2] | ((uint)u[3] << 16);
                v.z = (uint)u[4] | ((uint)u[5] << 16);
                v.w = (uint)u[6] | ((uint)u[7] << 16);
                *(uint4*)(xtb + (size_t)(n0 + nn) * CCH + c8) = v;   // full 256B rows
            }
        }
    } else {
        // ---- bucket fill chunk: counts[r] is cursor AND degree; row base r*CAP.
        int part  = sub & 7;           // round-robin -> XCD id
        int chunk = sub >> 3;
        int e0 = chunk * FILL_CS;
        int e1 = e0 + FILL_CS; if (e1 > E) e1 = E;
        for (int base = e0; base < e1; base += 1024) {
            int rr[4], gg[4];
            bool act[4];
            #pragma unroll
            for (int q = 0; q < 4; ++q) {
                int e = base + q * 256 + tid;
                bool in = (e < e1);
                int ec = in ? e : e0;
                rr[q] = ridx[ec];
                gg[q] = gidx[ec];
                act[q] = in && (rr[q] / psz == part);
            }
            #pragma unroll
            for (int q = 0; q < 4; ++q) {
                if (act[q]) {
                    int p = __hip_atomic_fetch_add(&counts[rr[q]], 1,
                                                   __ATOMIC_RELAXED,
                                                   __HIP_MEMORY_SCOPE_WORKGROUP);
                    if (p < CAP) bucket[rr[q] * CAP + p] = gg[q];
                }
            }
        }
    }
}

// ---------------- gather-mean over bf16 x_t: one wave per vertex, bf16 output
__global__ __launch_bounds__(256) void gather_mean(
        const uint2* __restrict__ xtb,      // [N][32] uint2 = bf16x4 quads
        const int*   __restrict__ counts,   // [N] degrees
        const int*   __restrict__ bucket,   // [N][CAP]
        ushort*      __restrict__ gmb,      // [N][128] bf16
        int N) {
    int wave = threadIdx.x >> 6;
    int l = threadIdx.x & 63;
    int lq = l & 31;          // channel quad
    int half = l >> 5;        // edge-pair half
    #pragma unroll
    for (int i = 0; i < 2; ++i) {
        int n = blockIdx.x * 8 + wave * 2 + i;
        if (n >= N) return;   // wave-uniform
        int deg = __builtin_amdgcn_readfirstlane(counts[n]);
        int dg  = (deg < CAP) ? deg : CAP;
        const int* row = bucket + n * CAP;
        float4 acc = make_float4(0.f, 0.f, 0.f, 0.f);
        int k = 0;
        for (; k + 16 <= dg; k += 16) {         // 8 outstanding 8B gathers/lane
            uint2 u[8];
            #pragma unroll
            for (int q = 0; q < 8; ++q) {
                int g = row[k + 2 * q + half];
                u[q] = xtb[(size_t)g * 32 + lq];
            }
            #pragma unroll
            for (int q = 0; q < 8; ++q) {
                acc.x += bflo(u[q].x); acc.y += bfhi(u[q].x);
                acc.z += bflo(u[q].y); acc.w += bfhi(u[q].y);
            }
        }
        for (; k + 8 <= dg; k += 8) {
            uint2 u[4];
            #pragma unroll
            for (int q = 0; q < 4; ++q) {
                int g = row[k + 2 * q + half];
                u[q] = xtb[(size_t)g * 32 + lq];
            }
            #pragma unroll
            for (int q = 0; q < 4; ++q) {
                acc.x += bflo(u[q].x); acc.y += bfhi(u[q].x);
                acc.z += bflo(u[q].y); acc.w += bfhi(u[q].y);
            }
        }
        for (; k + 2 <= dg; k += 2) {
            int g = row[k + half];
            uint2 u = xtb[(size_t)g * 32 + lq];
            acc.x += bflo(u.x); acc.y += bfhi(u.x);
            acc.z += bflo(u.y); acc.w += bfhi(u.y);
        }
        if (k < dg && half == 0) {
            int g = row[k];
            uint2 u = xtb[(size_t)g * 32 + lq];
            acc.x += bflo(u.x); acc.y += bfhi(u.x);
            acc.z += bflo(u.y); acc.w += bfhi(u.y);
        }
        acc.x += __shfl_xor(acc.x, 32);
        acc.y += __shfl_xor(acc.y, 32);
        acc.z += __shfl_xor(acc.z, 32);
        acc.w += __shfl_xor(acc.w, 32);
        float inv = (deg > 0) ? 1.f / (float)deg : 0.f;
        if (half == 0) {
            ushort4 r;
            r.x = f2bf(acc.x * inv);
            r.y = f2bf(acc.y * inv);
            r.z = f2bf(acc.z * inv);
            r.w = f2bf(acc.w * inv);
            *(ushort4*)(gmb + (size_t)n * CCH + lq * 4) = r;
        }
    }
}

// ---------------- MFMA gemm: out = mask * leaky(W_stack @ [x;gmean] + bias)
// N_TILE=64, 4 waves, each wave: 16 n-cols x 128 o-rows, K=256. No LDS, no barrier.
__global__ __launch_bounds__(256) void gemm_mfma(
        const ushort* __restrict__ wstb,    // [128][256] bf16
        const ushort* __restrict__ xtb,     // [N][128] bf16  (K 0..127)
        const ushort* __restrict__ gmb,     // [N][128] bf16  (K 128..255)
        const int*    __restrict__ counts,  // [N]
        const float*  __restrict__ bias,    // [128]
        float* __restrict__ out,            // [128][N]
        int N) {
    int t = threadIdx.x;
    int wv = t >> 6;       // wave 0..3 -> n-frag
    int l  = t & 63;
    int l15 = l & 15;      // A: M-row / B: N-col / D: N-col
    int lk  = l >> 4;      // k-group (0..3)
    int n = blockIdx.x * 64 + wv * 16 + l15;
    int nc = (n < N) ? n : (N - 1);          // clamped for loads

    f32x4 acc[8];
    #pragma unroll
    for (int mf = 0; mf < 8; ++mf) acc[mf] = (f32x4){0.f, 0.f, 0.f, 0.f};

    const ushort* brow_x = xtb + (size_t)nc * CCH + lk * 8;
    const ushort* brow_g = gmb + (size_t)nc * CCH + lk * 8;
    const ushort* arow   = wstb + (size_t)l15 * 256 + lk * 8;

    #pragma unroll
    for (int ks = 0; ks < 8; ++ks) {
        const ushort* bp = (ks < 4) ? (brow_x + ks * 32) : (brow_g + (ks - 4) * 32);
        bf16x8 b = *(const bf16x8*)bp;
        #pragma unroll
        for (int mf = 0; mf < 8; ++mf) {
            bf16x8 a = *(const bf16x8*)(arow + (size_t)mf * 16 * 256 + ks * 32);
            acc[mf] = __builtin_amdgcn_mfma_f32_16x16x32_bf16(a, b, acc[mf], 0, 0, 0);
        }
    }

    // epilogue: D row(o) = mf*16 + lk*4 + r, col(n) = lane&15
    if (n < N) {
        float m = (counts[n] > 0) ? 1.f : 0.f;
        #pragma unroll
        for (int mf = 0; mf < 8; ++mf) {
            #pragma unroll
            for (int r = 0; r < 4; ++r) {
                int o = mf * 16 + lk * 4 + r;
                float v = (acc[mf][r] + bias[o]) * m;
                v = (v >= 0.f) ? v : 0.3f * v;
                out[(size_t)o * N + n] = v;
            }
        }
    }
}

extern "C" void kernel_launch(void* const* d_in, const int* in_sizes, int n_in,
                              void* d_out, int out_size, void* d_ws, size_t ws_size,
                              hipStream_t stream) {
    const float* x      = (const float*)d_in[0];  // [1,128,N]
    const float* weight = (const float*)d_in[1];  // [128,256]
    const float* bias   = (const float*)d_in[2];  // [128]
    const int*   ridx   = (const int*)d_in[3];    // [E]
    const int*   gidx   = (const int*)d_in[4];    // [E]
    float* out = (float*)d_out;

    int N = in_sizes[0] / CCH;   // 50000
    int E = in_sizes[3];         // 800000

    char* ws = (char*)d_ws;
    size_t xtb_bytes = (((size_t)N * CCH * sizeof(ushort)) + 63) & ~(size_t)63;
    size_t n_bytes   = (((size_t)N * sizeof(int)) + 63) & ~(size_t)63;
    size_t bkt_bytes = (((size_t)N * CAP * sizeof(int)) + 63) & ~(size_t)63;
    size_t w_bytes   = (((size_t)CCH * 256 * sizeof(ushort)) + 63) & ~(size_t)63;

    size_t o = 0;
    ushort* xtb   = (ushort*)(ws + o); o += xtb_bytes;
    int*    counts= (int*)   (ws + o); o += n_bytes;
    int*    bucket= (int*)   (ws + o); o += bkt_bytes;
    ushort* wstb  = (ushort*)(ws + o); o += w_bytes;
    ushort* gmb   = (ushort*)(ws + o);

    int psz     = (N + 7) / 8;
    int nchunks = (E + FILL_CS - 1) / FILL_CS;
    int T = (N + 31) / 32;        // transpose blocks
    int F = nchunks * 8;          // fill blocks

    // 1. weights prep (bf16 W_stack) + zero counts
    prep_zero<<<128, 256, 0, stream>>>(weight, wstb, counts, N);

    // 2. fused transpose + bucket-CSR build (heterogeneous, interleaved blocks)
    transpose_fill<<<T + F, 256, 0, stream>>>(x, xtb, ridx, gidx,
                                              counts, bucket, N, E, psz, T, F);

    // 3. gather-mean (bf16 reads, fp32 accumulate, bf16 output)
    gather_mean<<<(N + 7) / 8, 256, 0, stream>>>(
        (const uint2*)xtb, counts, bucket, gmb, N);

    // 4. single bf16 MFMA GEMM + bias + mask + leaky
    gemm_mfma<<<(N + 63) / 64, 256, 0, stream>>>(
        wstb, xtb, gmb, counts, bias, out, N);
}